// Round 16
// baseline (42.266 us; speedup 1.0000x reference)
//
#include <hip/hip_runtime.h>

typedef unsigned short ushort_t;
typedef __bf16 bf16x8 __attribute__((ext_vector_type(8)));
typedef float f32x4 __attribute__((ext_vector_type(4)));

#define AS1 __attribute__((address_space(1)))
#define AS3 __attribute__((address_space(3)))

__device__ __forceinline__ ushort_t f2bf(float f) {
    unsigned u = __builtin_bit_cast(unsigned, f);
    u = (u + 0x7fffu + ((u >> 16) & 1u)) >> 16;
    return (ushort_t)u;
}

__device__ __forceinline__ void async16(void* lds, const void* g) {
    __builtin_amdgcn_global_load_lds((const AS1 unsigned int*)g,
                                     (AS3 unsigned int*)lds, 16, 0, 0);
}

__device__ __forceinline__ void softmax2(const float* __restrict__ sig, float& s0, float& s1) {
    float a = sig[0], b = sig[1];
    float m = fmaxf(a, b);
    float e0 = __expf(a - m), e1 = __expf(b - m);
    float inv = 1.0f / (e0 + e1);
    s0 = e0 * inv; s1 = e1 * inv;
}

// toeplitz value: W_toep[k][o]
__device__ __forceinline__ float toep_val(const float* __restrict__ Wseed, int k, int o) {
    return (k >= o) ? Wseed[(size_t)(k - o) << 10] : Wseed[o - k];
}

// ---------------- prep: W_core^T bf16 (x consumed fp32 by GEMM) ----------------
__global__ __launch_bounds__(256) void prep_w_kernel(const float* __restrict__ Wseed,
                                                     const float* __restrict__ Wsig,
                                                     ushort_t* __restrict__ Wt) {
    __shared__ float T[64][65];
    int bb = blockIdx.x;                        // 0..255
    int k0 = (bb >> 4) * 64;
    int o0 = (bb & 15) * 64;
    int t = threadIdx.x;
    #pragma unroll
    for (int i = 0; i < 4; ++i) {
        int lin = t + i * 256;
        int kr = lin >> 4;
        int c4 = lin & 15;
        float4 v = *(const float4*)&Wseed[(size_t)(k0 + kr) * 1024 + o0 + c4 * 4];
        T[kr][c4 * 4 + 0] = v.x;
        T[kr][c4 * 4 + 1] = v.y;
        T[kr][c4 * 4 + 2] = v.z;
        T[kr][c4 * 4 + 3] = v.w;
    }
    __syncthreads();
    float s0, s1; softmax2(Wsig, s0, s1);
    #pragma unroll
    for (int i = 0; i < 2; ++i) {
        int lin = t + i * 256;
        int oo = lin >> 3;
        int kq = (lin & 7) * 8;
        unsigned r[4];
        #pragma unroll
        for (int q = 0; q < 4; ++q) {
            float v0 = s0 * T[kq + 2 * q + 0][oo] + s1 * toep_val(Wseed, k0 + kq + 2 * q + 0, o0 + oo);
            float v1 = s0 * T[kq + 2 * q + 1][oo] + s1 * toep_val(Wseed, k0 + kq + 2 * q + 1, o0 + oo);
            r[q] = (unsigned)f2bf(v0) | ((unsigned)f2bf(v1) << 16);
        }
        *(uint4*)&Wt[(size_t)(o0 + oo) * 1024 + k0 + kq] = make_uint4(r[0], r[1], r[2], r[3]);
    }
}

// ---------------- main GEMM: R15 structure at 4 blocks/CU (BM=64) ----------------
// 64x128 tile, BK=32, 256 threads = 4 waves (2Mx2N, per-wave 32x64), grid 1024 =
// 4 blocks/CU (the m102 blocks/CU->TF axis: 1->320, 2->~500 (=R15), 4->~900).
// 4 independent barrier domains per CU fill each other's vmcnt-drain holes.
// A: fp32 x via async16, chunk ^= row&7 (2-way, free). cvt in-reg at use.
// B: bf16 Wt via async16, chunk ^= (row>>1)&3 (R15-verified).
// One vmcnt(0)+lgkmcnt(0)+barrier per K-step (2-phase dbuf). LDS 32 KB/block.
#define BM 64
#define BN 128
#define BK 32
#define NKT 32   // 1024 / 32

__global__ __launch_bounds__(256, 4) void gemm_kernel(const float* __restrict__ Xf,
                                                      const ushort_t* __restrict__ Wt,
                                                      const float* __restrict__ bseed,
                                                      const float* __restrict__ bsig,
                                                      const float* __restrict__ asig,
                                                      float* __restrict__ out) {
    // dbuf x (A 8KB fp32 + B 8KB bf16) = 32 KB
    __shared__ ushort_t lds[16384];
    ushort_t* At0 = lds;            // 4096 ushorts = 8KB (64 rows x 32 fp32)
    ushort_t* Bt0 = lds + 4096;     // 4096 ushorts = 8KB (128 rows x 32 bf16)
    ushort_t* At1 = lds + 8192;
    ushort_t* Bt1 = lds + 12288;

    const int t = threadIdx.x;        // 0..255
    const int wv = t >> 6;            // 0..3
    const int lane = t & 63;

    // XCD-aware swizzle (1024 blocks, 1024%8==0 -> bijective)
    const int orig = blockIdx.x;
    const int g = orig & 7;
    const int within = orig >> 3;            // 0..127
    const int rb = g * 16 + (within >> 3);   // row-block 0..127 (16 per XCD)
    const int cb = within & 7;               // col-block 0..7
    const int brow = rb * BM;
    const int bcol = cb * BN;

    // ---- A staging map: 8 threads per 128B row (rows 0..31 per call) ----
    const int ra = t >> 3;                        // 0..31
    const int ca = (t & 7) ^ (ra & 7);            // inverse-swizzled 16B chunk
    const float* gAsw = Xf + (size_t)(brow + ra) * 1024 + 4 * ca;

    // ---- B staging map: 4 threads per 64B row (rows 0..63 per call) ----
    const int rbb = t >> 2;                       // 0..63
    const int cbk = (t & 3) ^ ((rbb >> 1) & 3);   // inverse-swizzled 16B chunk
    const ushort_t* gBsw = Wt + (size_t)(bcol + rbb) * 1024 + 8 * cbk;

    f32x4 acc[2][4];
    #pragma unroll
    for (int i = 0; i < 2; ++i)
        #pragma unroll
        for (int j = 0; j < 4; ++j) acc[i][j] = (f32x4){0.f, 0.f, 0.f, 0.f};

    // wave decomposition: 2 M-groups x 2 N-groups; wave = 32 rows x 64 cols
    const int wr = (wv >> 1) * 32;     // 0,32
    const int wcn = (wv & 1) * 64;     // 0,64
    const int fr = lane & 15;
    const int kg = (lane >> 4) * 8;    // k-offset (elements)
    const int c0 = (lane >> 4) * 2;    // A 16B-chunk base

    // epilogue scalars precomputed + pinned
    float bs0, bs1, as0, as1;
    softmax2(bsig, bs0, bs1);
    softmax2(asig, as0, as1);
    float bias[4];
    #pragma unroll
    for (int ni = 0; ni < 4; ++ni)
        bias[ni] = bs0 * bseed[bcol + wcn + ni * 16 + fr];
    asm volatile("" :: "v"(bias[0]), "v"(bias[1]), "v"(bias[2]), "v"(bias[3]),
                       "v"(as0), "v"(as1));
    asm volatile("" ::: "memory");

// A: 2 calls x 4KB (256 threads x 16B); dest linear (ushort off = t*8 = ra*64 + chunk*8)
#define STAGEA(Abuf, ko)                                           \
    do {                                                           \
        async16((Abuf) + wv * 512,        gAsw + (ko));            \
        async16((Abuf) + 2048 + wv * 512, gAsw + 32768 + (ko));    \
    } while (0)

// B: 2 calls x 4KB; dest linear (ushort off = t*8 = rbb*32 + chunk*8)
#define STAGEB(Bbuf, ko)                                           \
    do {                                                           \
        async16((Bbuf) + wv * 512,        gBsw + (ko));            \
        async16((Bbuf) + 2048 + wv * 512, gBsw + 65536 + (ko));    \
    } while (0)

#define COMPUTE(Abuf, Bbuf)                                                        \
    do {                                                                           \
        const float* Af_ = (const float*)(Abuf);                                   \
        bf16x8 af[2], bf[4];                                                       \
        _Pragma("unroll")                                                          \
        for (int mi = 0; mi < 2; ++mi) {                                           \
            int row_ = wr + mi * 16 + fr;                                          \
            f32x4 lo_ = *(const f32x4*)&Af_[row_ * 32 + (((c0)     ^ (row_ & 7)) << 2)]; \
            f32x4 hi_ = *(const f32x4*)&Af_[row_ * 32 + (((c0 + 1) ^ (row_ & 7)) << 2)]; \
            bf16x8 a_;                                                             \
            _Pragma("unroll")                                                      \
            for (int j_ = 0; j_ < 4; ++j_) {                                       \
                a_[j_]     = (__bf16)lo_[j_];                                      \
                a_[4 + j_] = (__bf16)hi_[j_];                                      \
            }                                                                      \
            af[mi] = a_;                                                           \
        }                                                                          \
        _Pragma("unroll")                                                          \
        for (int ni = 0; ni < 4; ++ni) {                                           \
            int rb_ = wcn + ni * 16 + fr;                                          \
            int ch_ = ((kg >> 3) ^ ((rb_ >> 1) & 3)) << 3;                         \
            bf[ni] = *(const bf16x8*)&(Bbuf)[rb_ * 32 + ch_];                      \
        }                                                                          \
        _Pragma("unroll")                                                          \
        for (int mi = 0; mi < 2; ++mi)                                             \
            _Pragma("unroll")                                                      \
            for (int ni = 0; ni < 4; ++ni)                                         \
                acc[mi][ni] = __builtin_amdgcn_mfma_f32_16x16x32_bf16(             \
                    af[mi], bf[ni], acc[mi][ni], 0, 0, 0);                         \
    } while (0)

#define SYNC() do { asm volatile("s_waitcnt vmcnt(0) lgkmcnt(0)" ::: "memory");    \
                    __builtin_amdgcn_s_barrier(); } while (0)

    // prologue: K-step 0 into buf0
    STAGEA(At0, 0);
    STAGEB(Bt0, 0);
    SYNC();
    // main: 15 double-iterations
    for (int it = 0; it < 15; ++it) {
        STAGEA(At1, (2 * it + 1) * BK);       // next tile in flight across compute
        STAGEB(Bt1, (2 * it + 1) * BK);
        COMPUTE(At0, Bt0);
        SYNC();
        STAGEA(At0, (2 * it + 2) * BK);
        STAGEB(Bt0, (2 * it + 2) * BK);
        COMPUTE(At1, Bt1);
        SYNC();
    }
    // tail: K-steps 30, 31
    STAGEA(At1, 31 * BK);
    STAGEB(Bt1, 31 * BK);
    COMPUTE(At0, Bt0);
    SYNC();
    COMPUTE(At1, Bt1);

    // epilogue: bias + activation mixture
    #pragma unroll
    for (int ni = 0; ni < 4; ++ni) {
        int col = bcol + wcn + ni * 16 + fr;
        #pragma unroll
        for (int mi = 0; mi < 2; ++mi) {
            int row = brow + wr + mi * 16 + (lane >> 4) * 4;
            #pragma unroll
            for (int r = 0; r < 4; ++r) {
                float v = acc[mi][ni][r] + bias[ni];
                out[(size_t)(row + r) * 1024 + col] = as0 * v + as1 * fmaxf(v, 0.f);
            }
        }
    }
#undef STAGEA
#undef STAGEB
#undef COMPUTE
#undef SYNC
}

// ---------------- fallback (only if workspace too small): naive fp32 ----------------
__global__ __launch_bounds__(256) void naive_kernel(const float* __restrict__ x,
                                                    const float* __restrict__ Wseed,
                                                    const float* __restrict__ bseed,
                                                    const float* __restrict__ Wsig,
                                                    const float* __restrict__ bsig,
                                                    const float* __restrict__ asig,
                                                    float* __restrict__ out) {
    int idx = blockIdx.x * 256 + threadIdx.x;
    int b = idx >> 10, o = idx & 1023;
    float ws0, ws1, bs0, bs1, as0, as1;
    softmax2(Wsig, ws0, ws1);
    softmax2(bsig, bs0, bs1);
    softmax2(asig, as0, as1);
    float s = 0.f;
    const float* xr = x + (size_t)b * 1024;
    for (int k = 0; k < 1024; ++k) {
        float wc = ws0 * Wseed[((size_t)k << 10) + o] + ws1 * toep_val(Wseed, k, o);
        s += xr[k] * wc;
    }
    float v = s + bs0 * bseed[o];
    out[idx] = as0 * v + as1 * fmaxf(v, 0.f);
}

extern "C" void kernel_launch(void* const* d_in, const int* in_sizes, int n_in,
                              void* d_out, int out_size, void* d_ws, size_t ws_size,
                              hipStream_t stream) {
    const float* x     = (const float*)d_in[0];
    const float* Wseed = (const float*)d_in[1];
    const float* bseed = (const float*)d_in[2];
    const float* Wsig  = (const float*)d_in[3];
    const float* bsig  = (const float*)d_in[4];
    const float* Asig  = (const float*)d_in[5];
    float* out = (float*)d_out;

    const size_t need = (2u << 20) + 1024;
    if (ws_size < need) {
        naive_kernel<<<dim3(8192 * 1024 / 256), dim3(256), 0, stream>>>(
            x, Wseed, bseed, Wsig, bsig, Asig, out);
        return;
    }

    ushort_t* Wt = (ushort_t*)d_ws;   // 2 MB: W_core^T bf16 [1024][1024]

    prep_w_kernel<<<dim3(256), dim3(256), 0, stream>>>(Wseed, Wsig, Wt);
    gemm_kernel<<<dim3(1024), dim3(256), 0, stream>>>(x, Wt, bseed, bsig, Asig, out);
}

// Round 17
// 39.454 us; speedup vs baseline: 1.0713x; 1.0713x over previous
//
#include <hip/hip_runtime.h>

typedef unsigned short ushort_t;
typedef __bf16 bf16x8 __attribute__((ext_vector_type(8)));
typedef float f32x4 __attribute__((ext_vector_type(4)));

#define AS1 __attribute__((address_space(1)))
#define AS3 __attribute__((address_space(3)))

__device__ __forceinline__ ushort_t f2bf(float f) {
    unsigned u = __builtin_bit_cast(unsigned, f);
    u = (u + 0x7fffu + ((u >> 16) & 1u)) >> 16;
    return (ushort_t)u;
}

__device__ __forceinline__ void async16(void* lds, const void* g) {
    __builtin_amdgcn_global_load_lds((const AS1 unsigned int*)g,
                                     (AS3 unsigned int*)lds, 16, 0, 0);
}

__device__ __forceinline__ void softmax2(const float* __restrict__ sig, float& s0, float& s1) {
    float a = sig[0], b = sig[1];
    float m = fmaxf(a, b);
    float e0 = __expf(a - m), e1 = __expf(b - m);
    float inv = 1.0f / (e0 + e1);
    s0 = e0 * inv; s1 = e1 * inv;
}

// toeplitz value: W_toep[k][o]
__device__ __forceinline__ float toep_val(const float* __restrict__ Wseed, int k, int o) {
    return (k >= o) ? Wseed[(size_t)(k - o) << 10] : Wseed[o - k];
}

// ---------------- merged prep (R4-verified) ----------------
// blocks [0, 4096):    x fp32 [8192][1024] -> xb bf16, 8 elems/thread (coalesced)
// blocks [4096, 4352): 256 blocks, each a 64x64 (k,o) tile of W:
//   read Wseed rows coalesced, transpose via LDS, write Wt[o][k] bf16 coalesced.
__global__ __launch_bounds__(256) void prep_kernel(const float* __restrict__ x,
                                                   const float* __restrict__ Wseed,
                                                   const float* __restrict__ Wsig,
                                                   ushort_t* __restrict__ xb,
                                                   ushort_t* __restrict__ Wt) {
    int b = blockIdx.x;
    if (b < 4096) {
        int i = b * 256 + threadIdx.x;          // 1M threads, 8 elems each
        const float4* xp = (const float4*)x + (size_t)i * 2;
        float4 a = xp[0], c = xp[1];
        uint4 r;
        r.x = (unsigned)f2bf(a.x) | ((unsigned)f2bf(a.y) << 16);
        r.y = (unsigned)f2bf(a.z) | ((unsigned)f2bf(a.w) << 16);
        r.z = (unsigned)f2bf(c.x) | ((unsigned)f2bf(c.y) << 16);
        r.w = (unsigned)f2bf(c.z) | ((unsigned)f2bf(c.w) << 16);
        ((uint4*)xb)[i] = r;
        return;
    }
    __shared__ float T[64][65];
    int bb = b - 4096;                          // 0..255
    int k0 = (bb >> 4) * 64;
    int o0 = (bb & 15) * 64;
    int t = threadIdx.x;
    #pragma unroll
    for (int i = 0; i < 4; ++i) {
        int lin = t + i * 256;
        int kr = lin >> 4;
        int c4 = lin & 15;
        float4 v = *(const float4*)&Wseed[(size_t)(k0 + kr) * 1024 + o0 + c4 * 4];
        T[kr][c4 * 4 + 0] = v.x;
        T[kr][c4 * 4 + 1] = v.y;
        T[kr][c4 * 4 + 2] = v.z;
        T[kr][c4 * 4 + 3] = v.w;
    }
    __syncthreads();
    float s0, s1; softmax2(Wsig, s0, s1);
    #pragma unroll
    for (int i = 0; i < 2; ++i) {
        int lin = t + i * 256;
        int oo = lin >> 3;
        int kq = (lin & 7) * 8;
        unsigned r[4];
        #pragma unroll
        for (int q = 0; q < 4; ++q) {
            float v0 = s0 * T[kq + 2 * q + 0][oo] + s1 * toep_val(Wseed, k0 + kq + 2 * q + 0, o0 + oo);
            float v1 = s0 * T[kq + 2 * q + 1][oo] + s1 * toep_val(Wseed, k0 + kq + 2 * q + 1, o0 + oo);
            r[q] = (unsigned)f2bf(v0) | ((unsigned)f2bf(v1) << 16);
        }
        *(uint4*)&Wt[(size_t)(o0 + oo) * 1024 + k0 + kq] = make_uint4(r[0], r[1], r[2], r[3]);
    }
}

// ---------------- main GEMM: 128x128, BK=64, 16 syncs (drain-amortization A/B) ----
// 256 threads = 4 waves (2x2, each 64x64 out, 4x4 frags, 32 MFMA/step), grid 512.
// 16 K-tiles -> HALF the vmcnt(0)+barrier drains of R15 at full tile intensity.
// A and B both bf16 [128][64]: 128B rows, XOR swizzle chunk ^= row&7 on both
// (bank-verified 2-way = free). async16 staging: linear dest, pre-XOR'd source.
#define BM 128
#define BN 128
#define BK 64
#define NKT 16   // 1024 / 64

__global__ __launch_bounds__(256, 2) void gemm_kernel(const ushort_t* __restrict__ Xb,
                                                      const ushort_t* __restrict__ Wt,
                                                      const float* __restrict__ bseed,
                                                      const float* __restrict__ bsig,
                                                      const float* __restrict__ asig,
                                                      float* __restrict__ out) {
    // dbuf x (A 16KB + B 16KB) = 64 KB -> 2 blocks/CU
    __shared__ ushort_t lds[32768];
    ushort_t* At0 = lds;             // 8192 ushorts: [128 rows][64 k] bf16
    ushort_t* Bt0 = lds + 8192;
    ushort_t* At1 = lds + 16384;
    ushort_t* Bt1 = lds + 24576;

    const int t = threadIdx.x;        // 0..255
    const int wv = t >> 6;            // 0..3
    const int lane = t & 63;

    // XCD-aware swizzle (512 blocks, bijective)
    const int orig = blockIdx.x;
    const int g = orig & 7;
    const int within = orig >> 3;           // 0..63
    const int rb = g * 8 + (within >> 3);   // row-block 0..63
    const int cb = within & 7;              // col-block 0..7
    const int brow = rb * BM;
    const int bcol = cb * BN;

    // staging map: 8 threads per 128B row; row = q*32 + (t>>3) per call q.
    // (row&7) == ((t>>3)&7) for all q, so one pointer + call offsets works.
    const int rs = t >> 3;                        // 0..31
    const int cs = (t & 7) ^ (rs & 7);            // inverse-swizzled 16B chunk
    const ushort_t* gA = Xb + (size_t)(brow + rs) * 1024 + 8 * cs;
    const ushort_t* gB = Wt + (size_t)(bcol + rs) * 1024 + 8 * cs;

    f32x4 acc[4][4];
    #pragma unroll
    for (int i = 0; i < 4; ++i)
        #pragma unroll
        for (int j = 0; j < 4; ++j) acc[i][j] = (f32x4){0.f, 0.f, 0.f, 0.f};

    // wave decomposition (m97 geometry): wave = 64 rows x 64 cols
    const int wr = (wv >> 1) * 64;     // 0,64
    const int wcn = (wv & 1) * 64;     // 0,64
    const int fr = lane & 15;
    const int kq = lane >> 4;          // 0..3: k-chunk index within 32-elem half

    // epilogue scalars precomputed + pinned
    float bs0, bs1, as0, as1;
    softmax2(bsig, bs0, bs1);
    softmax2(asig, as0, as1);
    float bias[4];
    #pragma unroll
    for (int ni = 0; ni < 4; ++ni)
        bias[ni] = bs0 * bseed[bcol + wcn + ni * 16 + fr];
    asm volatile("" :: "v"(bias[0]), "v"(bias[1]), "v"(bias[2]), "v"(bias[3]),
                       "v"(as0), "v"(as1));
    asm volatile("" ::: "memory");

// 4 calls x 4KB each (256 thr x 16B); dest linear: ushort off = q*2048 + t*8
// == row*64 + chunk*8 with row = q*32 + (t>>3), chunk = t&7.
#define STAGE1(buf, gptr, ko)                                      \
    do {                                                           \
        async16((buf) + wv * 512,        (gptr) + (ko));           \
        async16((buf) + 2048 + wv * 512, (gptr) + 32768 + (ko));   \
        async16((buf) + 4096 + wv * 512, (gptr) + 65536 + (ko));   \
        async16((buf) + 6144 + wv * 512, (gptr) + 98304 + (ko));   \
    } while (0)

#define STAGE(Abuf, Bbuf, ko) do { STAGE1(Abuf, gA, ko); STAGE1(Bbuf, gB, ko); } while (0)

// fragment read: elem off = row*64 + 8*((kq + 4h) ^ (row&7)), h = k-half
#define COMPUTE(Abuf, Bbuf)                                                        \
    do {                                                                           \
        bf16x8 af[4][2], bf[4][2];                                                 \
        _Pragma("unroll")                                                          \
        for (int mi = 0; mi < 4; ++mi) {                                           \
            int row_ = wr + mi * 16 + fr;                                          \
            af[mi][0] = *(const bf16x8*)&(Abuf)[row_ * 64 + (((kq)     ^ (row_ & 7)) << 3)]; \
            af[mi][1] = *(const bf16x8*)&(Abuf)[row_ * 64 + (((kq + 4) ^ (row_ & 7)) << 3)]; \
        }                                                                          \
        _Pragma("unroll")                                                          \
        for (int ni = 0; ni < 4; ++ni) {                                           \
            int row_ = wcn + ni * 16 + fr;                                         \
            bf[ni][0] = *(const bf16x8*)&(Bbuf)[row_ * 64 + (((kq)     ^ (row_ & 7)) << 3)]; \
            bf[ni][1] = *(const bf16x8*)&(Bbuf)[row_ * 64 + (((kq + 4) ^ (row_ & 7)) << 3)]; \
        }                                                                          \
        _Pragma("unroll")                                                          \
        for (int mi = 0; mi < 4; ++mi)                                             \
            _Pragma("unroll")                                                      \
            for (int ni = 0; ni < 4; ++ni) {                                       \
                acc[mi][ni] = __builtin_amdgcn_mfma_f32_16x16x32_bf16(             \
                    af[mi][0], bf[ni][0], acc[mi][ni], 0, 0, 0);                   \
                acc[mi][ni] = __builtin_amdgcn_mfma_f32_16x16x32_bf16(             \
                    af[mi][1], bf[ni][1], acc[mi][ni], 0, 0, 0);                   \
            }                                                                      \
    } while (0)

#define SYNC() do { asm volatile("s_waitcnt vmcnt(0) lgkmcnt(0)" ::: "memory");    \
                    __builtin_amdgcn_s_barrier(); } while (0)

    // prologue: K-tile 0 into buf0
    STAGE(At0, Bt0, 0);
    SYNC();
    // main: 7 double-iterations (tiles 0..13)
    for (int it = 0; it < 7; ++it) {
        STAGE(At1, Bt1, (2 * it + 1) * BK);
        COMPUTE(At0, Bt0);
        SYNC();
        STAGE(At0, Bt0, (2 * it + 2) * BK);
        COMPUTE(At1, Bt1);
        SYNC();
    }
    // tail: tiles 14, 15
    STAGE(At1, Bt1, 15 * BK);
    COMPUTE(At0, Bt0);
    SYNC();
    COMPUTE(At1, Bt1);

    // epilogue: bias + activation mixture
    #pragma unroll
    for (int ni = 0; ni < 4; ++ni) {
        int col = bcol + wcn + ni * 16 + fr;
        #pragma unroll
        for (int mi = 0; mi < 4; ++mi) {
            int row = brow + wr + mi * 16 + (lane >> 4) * 4;
            #pragma unroll
            for (int r = 0; r < 4; ++r) {
                float v = acc[mi][ni][r] + bias[ni];
                out[(size_t)(row + r) * 1024 + col] = as0 * v + as1 * fmaxf(v, 0.f);
            }
        }
    }
#undef STAGE1
#undef STAGE
#undef COMPUTE
#undef SYNC
}

// ---------------- fallback (only if workspace too small): naive fp32 ----------------
__global__ __launch_bounds__(256) void naive_kernel(const float* __restrict__ x,
                                                    const float* __restrict__ Wseed,
                                                    const float* __restrict__ bseed,
                                                    const float* __restrict__ Wsig,
                                                    const float* __restrict__ bsig,
                                                    const float* __restrict__ asig,
                                                    float* __restrict__ out) {
    int idx = blockIdx.x * 256 + threadIdx.x;
    int b = idx >> 10, o = idx & 1023;
    float ws0, ws1, bs0, bs1, as0, as1;
    softmax2(Wsig, ws0, ws1);
    softmax2(bsig, bs0, bs1);
    softmax2(asig, as0, as1);
    float s = 0.f;
    const float* xr = x + (size_t)b * 1024;
    for (int k = 0; k < 1024; ++k) {
        float wc = ws0 * Wseed[((size_t)k << 10) + o] + ws1 * toep_val(Wseed, k, o);
        s += xr[k] * wc;
    }
    float v = s + bs0 * bseed[o];
    out[idx] = as0 * v + as1 * fmaxf(v, 0.f);
}

extern "C" void kernel_launch(void* const* d_in, const int* in_sizes, int n_in,
                              void* d_out, int out_size, void* d_ws, size_t ws_size,
                              hipStream_t stream) {
    const float* x     = (const float*)d_in[0];
    const float* Wseed = (const float*)d_in[1];
    const float* bseed = (const float*)d_in[2];
    const float* Wsig  = (const float*)d_in[3];
    const float* bsig  = (const float*)d_in[4];
    const float* Asig  = (const float*)d_in[5];
    float* out = (float*)d_out;

    const size_t need = (2u << 20) + (16u << 20) + 1024;
    if (ws_size < need) {
        naive_kernel<<<dim3(8192 * 1024 / 256), dim3(256), 0, stream>>>(
            x, Wseed, bseed, Wsig, bsig, Asig, out);
        return;
    }

    ushort_t* Wt = (ushort_t*)d_ws;                         // 2 MB: W_core^T bf16 [1024][1024]
    ushort_t* Xb = (ushort_t*)((char*)d_ws + (2u << 20));   // 16 MB: x bf16 [8192][1024]

    prep_kernel<<<dim3(4096 + 256), dim3(256), 0, stream>>>(x, Wseed, Wsig, Xb, Wt);
    gemm_kernel<<<dim3(512), dim3(256), 0, stream>>>(Xb, Wt, bseed, bsig, Asig, out);
}